// Round 1
// baseline (127.213 us; speedup 1.0000x reference)
//
#include <hip/hip_runtime.h>
#include <hip/hip_bf16.h>

// GEMM with fused int4 dequant:  C[M][N] = A[M][K] * W[N][K]^T
//   A: fp32 (2048 x 4096)
//   W: packed int4, one byte per int32 value (N x K/2), hi nibble = even k
//   scales_and_zeros: (K/G, N, 2) fp32, G = 128
// Structure: 128x128 block tile, BK=64, 4 waves (2x2) of 64x64 each,
// mfma_f32_16x16x32_bf16, single-buffered padded LDS, reg-staged loads
// (dequant + f32->bf16 conversion fused into staging).

using bf16x8 = __attribute__((ext_vector_type(8))) short;
using f32x4  = __attribute__((ext_vector_type(4))) float;

#define BM 128
#define BN 128
#define BK 64
#define LDK 72   // LDS row stride in bf16 elems: 64 + 8 pad -> 144 B (16B-aligned rows)

static __device__ __forceinline__ short f2bf(float f) {
    __hip_bfloat16 h = __float2bfloat16(f);
    return __builtin_bit_cast(short, h);
}

__global__ __launch_bounds__(256) void wq4_gemm(
    const float* __restrict__ A,
    const int*   __restrict__ W,
    const float* __restrict__ SZ,
    float* __restrict__ C,
    int M, int N, int K)
{
    __shared__ short sA[BM * LDK];
    __shared__ short sB[BN * LDK];

    const int tid  = threadIdx.x;
    const int lane = tid & 63;
    const int wave = tid >> 6;
    const int wr   = (wave >> 1) << 6;   // wave row offset: 0 or 64
    const int wc   = (wave & 1) << 6;    // wave col offset: 0 or 64

    const int bm = blockIdx.y * BM;
    const int bn = blockIdx.x * BN;

    const int Kh = K >> 1;

    // A staging: 4 threads per row, 16 floats each; 2 row-passes (64 rows/pass)
    const int ar = tid >> 2;            // 0..63
    const int ac = (tid & 3) << 4;      // 0,16,32,48
    // B staging: 2 threads per row, 16 packed int32 (= 32 bf16) each
    const int br = tid >> 1;            // 0..127
    const int bh = (tid & 1) << 4;      // int32 offset within row: 0 or 16

    const float* Arow0 = A + (size_t)(bm + ar) * K + ac;
    const float* Arow1 = A + (size_t)(bm + 64 + ar) * K + ac;
    const int*   Wrow  = W + (size_t)(bn + br) * Kh + bh;
    const float* SZrow = SZ + (size_t)(bn + br) * 2;

    f32x4 acc[4][4] = {};

    for (int k0 = 0; k0 < K; k0 += BK) {
        // ---- stage A: 128 x 64 fp32 -> bf16 ----
        {
            const float4* s0 = (const float4*)(Arow0 + k0);
            const float4* s1 = (const float4*)(Arow1 + k0);
            float4 a0 = s0[0], a1 = s0[1], a2 = s0[2], a3 = s0[3];
            float4 b0 = s1[0], b1 = s1[1], b2 = s1[2], b3 = s1[3];
            auto cvt8 = [](float4 u, float4 v) -> bf16x8 {
                bf16x8 r;
                r[0] = f2bf(u.x); r[1] = f2bf(u.y); r[2] = f2bf(u.z); r[3] = f2bf(u.w);
                r[4] = f2bf(v.x); r[5] = f2bf(v.y); r[6] = f2bf(v.z); r[7] = f2bf(v.w);
                return r;
            };
            *(bf16x8*)&sA[ar * LDK + ac]            = cvt8(a0, a1);
            *(bf16x8*)&sA[ar * LDK + ac + 8]        = cvt8(a2, a3);
            *(bf16x8*)&sA[(64 + ar) * LDK + ac]     = cvt8(b0, b1);
            *(bf16x8*)&sA[(64 + ar) * LDK + ac + 8] = cvt8(b2, b3);
        }
        // ---- stage B: dequant 128 x 64 int4 -> bf16 ----
        {
            const int g = k0 >> 7;                       // group index (G=128, BK=64)
            const float2 sz = *(const float2*)(SZrow + (size_t)g * N * 2);
            const float scale = sz.x;
            const float zs    = sz.y - 8.0f * sz.x;      // fold (q-8)*s+z -> q*s+zs
            const int4* src = (const int4*)(Wrow + (k0 >> 1));
            #pragma unroll
            for (int i = 0; i < 4; ++i) {
                int4 p = src[i];
                int vals[4] = {p.x, p.y, p.z, p.w};
                bf16x8 r;
                #pragma unroll
                for (int j = 0; j < 4; ++j) {
                    int v = vals[j];
                    float hi = (float)((v >> 4) & 0xF);   // even k
                    float lo = (float)(v & 0xF);          // odd k
                    r[2 * j]     = f2bf(hi * scale + zs);
                    r[2 * j + 1] = f2bf(lo * scale + zs);
                }
                *(bf16x8*)&sB[br * LDK + (bh << 1) + (i << 3)] = r;
            }
        }
        __syncthreads();

        // ---- compute: 2 k-subtiles of 32, 16 MFMA each per wave ----
        #pragma unroll
        for (int ks = 0; ks < 2; ++ks) {
            const int col = (ks << 5) + ((lane >> 4) << 3);
            bf16x8 af[4], bfr[4];
            #pragma unroll
            for (int m = 0; m < 4; ++m)
                af[m] = *(const bf16x8*)&sA[(wr + m * 16 + (lane & 15)) * LDK + col];
            #pragma unroll
            for (int n = 0; n < 4; ++n)
                bfr[n] = *(const bf16x8*)&sB[(wc + n * 16 + (lane & 15)) * LDK + col];
            #pragma unroll
            for (int m = 0; m < 4; ++m)
                #pragma unroll
                for (int n = 0; n < 4; ++n)
                    acc[m][n] = __builtin_amdgcn_mfma_f32_16x16x32_bf16(
                        af[m], bfr[n], acc[m][n], 0, 0, 0);
        }
        __syncthreads();
    }

    // ---- epilogue: C/D layout col = lane&15, row = (lane>>4)*4 + reg ----
    {
        float* Cp = C + (size_t)(bm + wr) * N + bn + wc;
        const int cr = (lane >> 4) << 2;
        const int cc = lane & 15;
        #pragma unroll
        for (int m = 0; m < 4; ++m) {
            #pragma unroll
            for (int j = 0; j < 4; ++j) {
                float* dst = Cp + (size_t)(m * 16 + cr + j) * N + cc;
                #pragma unroll
                for (int n = 0; n < 4; ++n)
                    dst[n * 16] = acc[m][n][j];
            }
        }
    }
}

extern "C" void kernel_launch(void* const* d_in, const int* in_sizes, int n_in,
                              void* d_out, int out_size, void* d_ws, size_t ws_size,
                              hipStream_t stream) {
    const float* A  = (const float*)d_in[0];
    const int*   W  = (const int*)d_in[1];
    const float* SZ = (const float*)d_in[2];
    float* C = (float*)d_out;

    const int K = 4096;
    const int N = 4096;
    const int M = in_sizes[0] / K;   // 2048

    dim3 grid(N / BN, M / BM);
    wq4_gemm<<<grid, dim3(256), 0, stream>>>(A, W, SZ, C, M, N, K);
}

// Round 2
// 111.264 us; speedup vs baseline: 1.1433x; 1.1433x over previous
//
#include <hip/hip_runtime.h>
#include <hip/hip_bf16.h>

// Weight-only int4 GEMM, split into:
//   1) dequant_w : packed int4 -> bf16 Wd[N][K] in d_ws (32 MB)
//   2) cvt_a     : fp32 A -> bf16 Ab[M][K] in d_ws (16 MB)
//   3) gemm_bf16 : m97-structure bf16 GEMM (128x128 tile, BK=64,
//                  global_load_lds width=16, 4 waves, 16x16x32 MFMA)
// Fallback to the round-1 fused kernel if ws_size is too small.

using bf16x8 = __attribute__((ext_vector_type(8))) short;
using f32x4  = __attribute__((ext_vector_type(4))) float;

#define KK 4096
#define NN 4096
#define GG 128

static __device__ __forceinline__ short f2bf(float f) {
    __hip_bfloat16 h = __float2bfloat16(f);
    return __builtin_bit_cast(short, h);
}

#define GLDS16(gptr, lptr) __builtin_amdgcn_global_load_lds( \
    (const __attribute__((address_space(1))) void*)(gptr),   \
    (__attribute__((address_space(3))) void*)(lptr), 16, 0, 0)

// ---------------- pre-pass 1: dequant W -> bf16 ----------------
// grid: NN * (KK/2/4) / 256 = 8192 blocks; each thread: 4 int32 -> 8 bf16
__global__ __launch_bounds__(256) void dequant_w(
    const int* __restrict__ W, const float* __restrict__ SZ,
    short* __restrict__ Wd)
{
    const int idx = blockIdx.x * 256 + threadIdx.x;   // [0, NN*512)
    const int n   = idx >> 9;
    const int q4  = idx & 511;
    const int kh0 = q4 << 2;                          // int32 index in row
    const int g   = kh0 >> 6;                         // group = (2*kh0)/128
    const float2 sz = *(const float2*)(SZ + ((size_t)g * NN + n) * 2);
    const float scale = sz.x;
    const float zs    = sz.y - 8.0f * sz.x;           // (q-8)*s+z = q*s+zs
    int4 p = *(const int4*)(W + (size_t)n * (KK / 2) + kh0);
    int vals[4] = {p.x, p.y, p.z, p.w};
    bf16x8 r;
    #pragma unroll
    for (int j = 0; j < 4; ++j) {
        int v = vals[j];
        r[2 * j]     = f2bf((float)((v >> 4) & 0xF) * scale + zs); // even k
        r[2 * j + 1] = f2bf((float)(v & 0xF) * scale + zs);        // odd k
    }
    *(bf16x8*)&Wd[(size_t)n * KK + (kh0 << 1)] = r;
}

// ---------------- pre-pass 2: A fp32 -> bf16 ----------------
__global__ __launch_bounds__(256) void cvt_a(
    const float* __restrict__ A, short* __restrict__ Ab)
{
    const int idx = blockIdx.x * 256 + threadIdx.x;   // each: 8 floats
    const float4* s = (const float4*)(A + (size_t)idx * 8);
    float4 u = s[0], v = s[1];
    bf16x8 r;
    r[0] = f2bf(u.x); r[1] = f2bf(u.y); r[2] = f2bf(u.z); r[3] = f2bf(u.w);
    r[4] = f2bf(v.x); r[5] = f2bf(v.y); r[6] = f2bf(v.z); r[7] = f2bf(v.w);
    *(bf16x8*)&Ab[(size_t)idx * 8] = r;
}

// ---------------- main bf16 GEMM (m97 structure) ----------------
__global__ __launch_bounds__(256) void gemm_bf16(
    const short* __restrict__ Ab, const short* __restrict__ Bb,
    float* __restrict__ C)
{
    __shared__ short sA[128 * 64];
    __shared__ short sB[128 * 64];

    const int tid  = threadIdx.x;
    const int lane = tid & 63;
    const int wave = tid >> 6;
    const int bm = blockIdx.y * 128;
    const int bn = blockIdx.x * 128;
    const int wr = (wave >> 1) << 6;
    const int wc = (wave & 1) << 6;

    // staging: chunk c = wave*4 + l covers rows [c*8, c*8+8) of the tile.
    // lane i -> within-chunk elems [i*8, i*8+8) -> row c*8 + i/8, col (i&7)*8
    const int srow = (wave << 5) + (lane >> 3);   // row for l=0
    const int scol = (lane & 7) << 3;
    const short* gA = Ab + (size_t)(bm + srow) * KK + scol;
    const short* gB = Bb + (size_t)(bn + srow) * KK + scol;
    short* lA = sA + ((wave << 2) * 512);         // chunk (wave*4+l) base
    short* lB = sB + ((wave << 2) * 512);

    f32x4 acc[4][4] = {};

    for (int k0 = 0; k0 < KK; k0 += 64) {
        #pragma unroll
        for (int l = 0; l < 4; ++l) {
            GLDS16(gA + (size_t)(l * 8) * KK + k0, lA + l * 512);
            GLDS16(gB + (size_t)(l * 8) * KK + k0, lB + l * 512);
        }
        __syncthreads();
        #pragma unroll
        for (int ks = 0; ks < 2; ++ks) {
            const int col = (ks << 5) + ((lane >> 4) << 3);
            bf16x8 af[4], bfr[4];
            #pragma unroll
            for (int m = 0; m < 4; ++m)
                af[m] = *(const bf16x8*)&sA[(wr + m * 16 + (lane & 15)) * 64 + col];
            #pragma unroll
            for (int n = 0; n < 4; ++n)
                bfr[n] = *(const bf16x8*)&sB[(wc + n * 16 + (lane & 15)) * 64 + col];
            #pragma unroll
            for (int m = 0; m < 4; ++m)
                #pragma unroll
                for (int n = 0; n < 4; ++n)
                    acc[m][n] = __builtin_amdgcn_mfma_f32_16x16x32_bf16(
                        af[m], bfr[n], acc[m][n], 0, 0, 0);
        }
        __syncthreads();
    }

    // epilogue: C/D layout col = lane&15, row = (lane>>4)*4 + reg
    float* Cp = C + (size_t)(bm + wr) * NN + bn + wc;
    const int cr = (lane >> 4) << 2;
    const int cc = lane & 15;
    #pragma unroll
    for (int m = 0; m < 4; ++m) {
        #pragma unroll
        for (int j = 0; j < 4; ++j) {
            float* dst = Cp + (size_t)(m * 16 + cr + j) * NN + cc;
            #pragma unroll
            for (int n = 0; n < 4; ++n)
                dst[n * 16] = acc[m][n][j];
        }
    }
}

// ---------------- fallback: round-1 fused kernel ----------------
#define LDKF 72
__global__ __launch_bounds__(256) void wq4_gemm_fused(
    const float* __restrict__ A, const int* __restrict__ W,
    const float* __restrict__ SZ, float* __restrict__ C, int M)
{
    __shared__ short sA[128 * LDKF];
    __shared__ short sB[128 * LDKF];
    const int tid = threadIdx.x, lane = tid & 63, wave = tid >> 6;
    const int wr = (wave >> 1) << 6, wc = (wave & 1) << 6;
    const int bm = blockIdx.y * 128, bn = blockIdx.x * 128;
    const int ar = tid >> 2, ac = (tid & 3) << 4;
    const int br = tid >> 1, bh = (tid & 1) << 4;
    const float* Arow0 = A + (size_t)(bm + ar) * KK + ac;
    const float* Arow1 = A + (size_t)(bm + 64 + ar) * KK + ac;
    const int*   Wrow  = W + (size_t)(bn + br) * (KK / 2) + bh;
    const float* SZrow = SZ + (size_t)(bn + br) * 2;
    f32x4 acc[4][4] = {};
    for (int k0 = 0; k0 < KK; k0 += 64) {
        {
            const float4* s0 = (const float4*)(Arow0 + k0);
            const float4* s1 = (const float4*)(Arow1 + k0);
            float4 a0 = s0[0], a1 = s0[1], a2 = s0[2], a3 = s0[3];
            float4 b0 = s1[0], b1 = s1[1], b2 = s1[2], b3 = s1[3];
            auto cvt8 = [](float4 u, float4 v) -> bf16x8 {
                bf16x8 r;
                r[0] = f2bf(u.x); r[1] = f2bf(u.y); r[2] = f2bf(u.z); r[3] = f2bf(u.w);
                r[4] = f2bf(v.x); r[5] = f2bf(v.y); r[6] = f2bf(v.z); r[7] = f2bf(v.w);
                return r;
            };
            *(bf16x8*)&sA[ar * LDKF + ac]             = cvt8(a0, a1);
            *(bf16x8*)&sA[ar * LDKF + ac + 8]         = cvt8(a2, a3);
            *(bf16x8*)&sA[(64 + ar) * LDKF + ac]      = cvt8(b0, b1);
            *(bf16x8*)&sA[(64 + ar) * LDKF + ac + 8]  = cvt8(b2, b3);
        }
        {
            const int g = k0 >> 7;
            const float2 sz = *(const float2*)(SZrow + (size_t)g * NN * 2);
            const float scale = sz.x, zs = sz.y - 8.0f * sz.x;
            const int4* src = (const int4*)(Wrow + (k0 >> 1));
            #pragma unroll
            for (int i = 0; i < 4; ++i) {
                int4 p = src[i];
                int vals[4] = {p.x, p.y, p.z, p.w};
                bf16x8 r;
                #pragma unroll
                for (int j = 0; j < 4; ++j) {
                    int v = vals[j];
                    r[2 * j]     = f2bf((float)((v >> 4) & 0xF) * scale + zs);
                    r[2 * j + 1] = f2bf((float)(v & 0xF) * scale + zs);
                }
                *(bf16x8*)&sB[br * LDKF + (bh << 1) + (i << 3)] = r;
            }
        }
        __syncthreads();
        #pragma unroll
        for (int ks = 0; ks < 2; ++ks) {
            const int col = (ks << 5) + ((lane >> 4) << 3);
            bf16x8 af[4], bfr[4];
            #pragma unroll
            for (int m = 0; m < 4; ++m)
                af[m] = *(const bf16x8*)&sA[(wr + m * 16 + (lane & 15)) * LDKF + col];
            #pragma unroll
            for (int n = 0; n < 4; ++n)
                bfr[n] = *(const bf16x8*)&sB[(wc + n * 16 + (lane & 15)) * LDKF + col];
            #pragma unroll
            for (int m = 0; m < 4; ++m)
                #pragma unroll
                for (int n = 0; n < 4; ++n)
                    acc[m][n] = __builtin_amdgcn_mfma_f32_16x16x32_bf16(
                        af[m], bfr[n], acc[m][n], 0, 0, 0);
        }
        __syncthreads();
    }
    float* Cp = C + (size_t)(bm + wr) * NN + bn + wc;
    const int cr = (lane >> 4) << 2, cc = lane & 15;
    #pragma unroll
    for (int m = 0; m < 4; ++m)
        #pragma unroll
        for (int j = 0; j < 4; ++j) {
            float* dst = Cp + (size_t)(m * 16 + cr + j) * NN + cc;
            #pragma unroll
            for (int n = 0; n < 4; ++n) dst[n * 16] = acc[m][n][j];
        }
}

extern "C" void kernel_launch(void* const* d_in, const int* in_sizes, int n_in,
                              void* d_out, int out_size, void* d_ws, size_t ws_size,
                              hipStream_t stream) {
    const float* A  = (const float*)d_in[0];
    const int*   W  = (const int*)d_in[1];
    const float* SZ = (const float*)d_in[2];
    float* C = (float*)d_out;

    const int M = in_sizes[0] / KK;   // 2048

    const size_t wd_elems = (size_t)NN * KK;
    const size_t ab_elems = (size_t)M * KK;
    const size_t need = (wd_elems + ab_elems) * sizeof(short);

    if (ws_size >= need) {
        short* Wd = (short*)d_ws;
        short* Ab = Wd + wd_elems;
        dequant_w<<<NN * (KK / 8) / 256, 256, 0, stream>>>(W, SZ, Wd);
        cvt_a<<<(int)(ab_elems / 8 / 256), 256, 0, stream>>>(A, Ab);
        dim3 grid(NN / 128, M / 128);
        gemm_bf16<<<grid, dim3(256), 0, stream>>>(Ab, Wd, C);
    } else {
        dim3 grid(NN / 128, M / 128);
        wq4_gemm_fused<<<grid, dim3(256), 0, stream>>>(A, W, SZ, C, M);
    }
}

// Round 3
// 102.419 us; speedup vs baseline: 1.2421x; 1.0864x over previous
//
#include <hip/hip_runtime.h>
#include <hip/hip_bf16.h>

// Weight-only int4 GEMM (M=2048, N=4096, K=4096, G=128):
//   1) dequant_w : packed int4 -> bf16 Wd[N][K] in d_ws
//   2) cvt_a     : fp32 A -> bf16 Ab[M][K] in d_ws
//   3) gemm_8ph  : 8-phase-style pipelined bf16 GEMM (m201 port):
//        BM=256 x BN=128 tile, BK=64, 512 thr / 8 waves (4M x 2N, 64x64/wave)
//        3-deep LDS ring (144 KiB), counted vmcnt(6), chunk-XOR LDS swizzle
//        (pre-swizzled global src + swizzled ds_read), setprio around MFMA.

using bf16x8 = __attribute__((ext_vector_type(8))) short;
using f32x4  = __attribute__((ext_vector_type(4))) float;

#define KK 4096
#define NN 4096
#define NT (KK / 64)

static __device__ __forceinline__ short f2bf(float f) {
    __hip_bfloat16 h = __float2bfloat16(f);
    return __builtin_bit_cast(short, h);
}

#define GLDS16(gptr, lptr) __builtin_amdgcn_global_load_lds( \
    (const __attribute__((address_space(1))) void*)(gptr),   \
    (__attribute__((address_space(3))) void*)(lptr), 16, 0, 0)

#define MFMA16 __builtin_amdgcn_mfma_f32_16x16x32_bf16

// ---------------- pre-pass 1: dequant W -> bf16 ----------------
__global__ __launch_bounds__(256) void dequant_w(
    const int* __restrict__ W, const float* __restrict__ SZ,
    short* __restrict__ Wd)
{
    const int idx = blockIdx.x * 256 + threadIdx.x;   // [0, NN*512)
    const int n   = idx >> 9;
    const int q4  = idx & 511;
    const int kh0 = q4 << 2;                          // int32 index in row
    const int g   = kh0 >> 6;                         // group (G=128)
    const float2 sz = *(const float2*)(SZ + ((size_t)g * NN + n) * 2);
    const float scale = sz.x;
    const float zs    = sz.y - 8.0f * sz.x;           // (q-8)*s+z = q*s+zs
    int4 p = *(const int4*)(W + (size_t)n * (KK / 2) + kh0);
    int vals[4] = {p.x, p.y, p.z, p.w};
    bf16x8 r;
    #pragma unroll
    for (int j = 0; j < 4; ++j) {
        int v = vals[j];
        r[2 * j]     = f2bf((float)((v >> 4) & 0xF) * scale + zs); // even k
        r[2 * j + 1] = f2bf((float)(v & 0xF) * scale + zs);        // odd k
    }
    *(bf16x8*)&Wd[(size_t)n * KK + (kh0 << 1)] = r;
}

// ---------------- pre-pass 2: A fp32 -> bf16 ----------------
__global__ __launch_bounds__(256) void cvt_a(
    const float* __restrict__ A, short* __restrict__ Ab)
{
    const int idx = blockIdx.x * 256 + threadIdx.x;
    const float4* s = (const float4*)(A + (size_t)idx * 8);
    float4 u = s[0], v = s[1];
    bf16x8 r;
    r[0] = f2bf(u.x); r[1] = f2bf(u.y); r[2] = f2bf(u.z); r[3] = f2bf(u.w);
    r[4] = f2bf(v.x); r[5] = f2bf(v.y); r[6] = f2bf(v.z); r[7] = f2bf(v.w);
    *(bf16x8*)&Ab[(size_t)idx * 8] = r;
}

// ---------------- main pipelined GEMM ----------------
// LDS layout per K-tile buffer: A: 256 rows x 64 bf16 (row = 8 x 16B chunks),
// B: 128 rows x 64 bf16. Chunk swizzle: LDS(row, c) holds global(row, c^(row&7)).
__global__ __launch_bounds__(512, 2) void gemm_8ph(
    const short* __restrict__ Ab, const short* __restrict__ Bb,
    float* __restrict__ C)
{
    __shared__ short sA[3 * 256 * 64];   // 96 KiB
    __shared__ short sB[3 * 128 * 64];   // 48 KiB

    const int tid  = threadIdx.x;
    const int lane = tid & 63;
    const int wave = tid >> 6;           // 0..7
    const int wm   = wave >> 1;          // m-offset wm*64
    const int wn   = wave & 1;           // n-offset wn*64
    const int bm   = blockIdx.y * 256;
    const int bn   = blockIdx.x * 128;

    // staging: per gload_lds instr, wave covers 8 rows x 8 chunks linearly in
    // LDS; global source pre-swizzled: lane -> row +(lane>>3), chunk (lane&7)^(lane>>3)
    const int sl = lane >> 3;
    const int sc = (lane & 7) ^ sl;
    const short* aSt = Ab + (size_t)(bm + wave * 32 + sl) * KK + sc * 8;
    const short* bSt = Bb + (size_t)(bn + wave * 16 + sl) * KK + sc * 8;

    // fragment reads: row = frag*16 + (lane&15); logical chunk = ks*4 + (lane>>4);
    // phys chunk = logical ^ (row&7) = logical ^ (lane&7). Offsets in shorts.
    const int l15 = lane & 15;
    const int pc0 = (((lane >> 4)) ^ (lane & 7)) * 8;       // ks=0
    const int pc1 = ((4 | (lane >> 4)) ^ (lane & 7)) * 8;   // ks=1
    const int aRd = wm * 4096 + l15 * 64;
    const int bRd = wn * 4096 + l15 * 64;

    f32x4 acc[4][4] = {};
    bf16x8 aF[2][2], bF[2][2][2];

    // ---- prologue: stage K-tiles 0 and 1 (12 loads/thread in flight) ----
    #pragma unroll
    for (int l = 0; l < 4; ++l)
        GLDS16(aSt + l * 8 * KK,      &sA[(wave * 32 + l * 8) * 64]);
    #pragma unroll
    for (int l = 0; l < 2; ++l)
        GLDS16(bSt + l * 8 * KK,      &sB[(wave * 16 + l * 8) * 64]);
    #pragma unroll
    for (int l = 0; l < 4; ++l)
        GLDS16(aSt + l * 8 * KK + 64, &sA[16384 + (wave * 32 + l * 8) * 64]);
    #pragma unroll
    for (int l = 0; l < 2; ++l)
        GLDS16(bSt + l * 8 * KK + 64, &sB[8192 + (wave * 16 + l * 8) * 64]);
    asm volatile("s_waitcnt vmcnt(6)" ::: "memory");   // tile 0 landed
    __builtin_amdgcn_s_barrier();

    int cur = 0;
    for (int t = 0; t < NT; ++t) {
        const int nxt = (cur == 0) ? 2 : cur - 1;      // (t+2)%3
        const short* sAc = &sA[cur * 16384];
        const short* sBc = &sB[cur * 8192];
        short* sAn = &sA[nxt * 16384];
        short* sBn = &sB[nxt * 8192];
        const bool st = (t + 2 < NT);
        const int gk = (t + 2) * 64;

        // ---------- phase 0: m-frags 0,1 x n-frags 0,1 ----------
        aF[0][0] = *(const bf16x8*)&sAc[aRd + pc0];
        aF[0][1] = *(const bf16x8*)&sAc[aRd + pc1];
        aF[1][0] = *(const bf16x8*)&sAc[aRd + 1024 + pc0];
        aF[1][1] = *(const bf16x8*)&sAc[aRd + 1024 + pc1];
        bF[0][0][0] = *(const bf16x8*)&sBc[bRd + pc0];
        bF[0][0][1] = *(const bf16x8*)&sBc[bRd + pc1];
        bF[0][1][0] = *(const bf16x8*)&sBc[bRd + 1024 + pc0];
        bF[0][1][1] = *(const bf16x8*)&sBc[bRd + 1024 + pc1];
        if (st) {
            GLDS16(aSt + 0 * 8 * KK + gk, sAn + (wave * 32 + 0) * 64);
            GLDS16(aSt + 1 * 8 * KK + gk, sAn + (wave * 32 + 8) * 64);
        }
        __builtin_amdgcn_s_barrier();
        asm volatile("s_waitcnt lgkmcnt(0)" ::: "memory");
        __builtin_amdgcn_s_setprio(1);
        acc[0][0] = MFMA16(aF[0][0], bF[0][0][0], acc[0][0], 0, 0, 0);
        acc[0][0] = MFMA16(aF[0][1], bF[0][0][1], acc[0][0], 0, 0, 0);
        acc[0][1] = MFMA16(aF[0][0], bF[0][1][0], acc[0][1], 0, 0, 0);
        acc[0][1] = MFMA16(aF[0][1], bF[0][1][1], acc[0][1], 0, 0, 0);
        acc[1][0] = MFMA16(aF[1][0], bF[0][0][0], acc[1][0], 0, 0, 0);
        acc[1][0] = MFMA16(aF[1][1], bF[0][0][1], acc[1][0], 0, 0, 0);
        acc[1][1] = MFMA16(aF[1][0], bF[0][1][0], acc[1][1], 0, 0, 0);
        acc[1][1] = MFMA16(aF[1][1], bF[0][1][1], acc[1][1], 0, 0, 0);
        __builtin_amdgcn_s_setprio(0);
        __builtin_amdgcn_s_barrier();

        // ---------- phase 1: m-frags 0,1 x n-frags 2,3 ----------
        bF[1][0][0] = *(const bf16x8*)&sBc[bRd + 2048 + pc0];
        bF[1][0][1] = *(const bf16x8*)&sBc[bRd + 2048 + pc1];
        bF[1][1][0] = *(const bf16x8*)&sBc[bRd + 3072 + pc0];
        bF[1][1][1] = *(const bf16x8*)&sBc[bRd + 3072 + pc1];
        if (st) {
            GLDS16(aSt + 2 * 8 * KK + gk, sAn + (wave * 32 + 16) * 64);
            GLDS16(aSt + 3 * 8 * KK + gk, sAn + (wave * 32 + 24) * 64);
        }
        __builtin_amdgcn_s_barrier();
        asm volatile("s_waitcnt lgkmcnt(0)" ::: "memory");
        __builtin_amdgcn_s_setprio(1);
        acc[0][2] = MFMA16(aF[0][0], bF[1][0][0], acc[0][2], 0, 0, 0);
        acc[0][2] = MFMA16(aF[0][1], bF[1][0][1], acc[0][2], 0, 0, 0);
        acc[0][3] = MFMA16(aF[0][0], bF[1][1][0], acc[0][3], 0, 0, 0);
        acc[0][3] = MFMA16(aF[0][1], bF[1][1][1], acc[0][3], 0, 0, 0);
        acc[1][2] = MFMA16(aF[1][0], bF[1][0][0], acc[1][2], 0, 0, 0);
        acc[1][2] = MFMA16(aF[1][1], bF[1][0][1], acc[1][2], 0, 0, 0);
        acc[1][3] = MFMA16(aF[1][0], bF[1][1][0], acc[1][3], 0, 0, 0);
        acc[1][3] = MFMA16(aF[1][1], bF[1][1][1], acc[1][3], 0, 0, 0);
        __builtin_amdgcn_s_setprio(0);
        __builtin_amdgcn_s_barrier();

        // ---------- phase 2: m-frags 2,3 x n-frags 2,3 ----------
        aF[0][0] = *(const bf16x8*)&sAc[aRd + 2048 + pc0];
        aF[0][1] = *(const bf16x8*)&sAc[aRd + 2048 + pc1];
        aF[1][0] = *(const bf16x8*)&sAc[aRd + 3072 + pc0];
        aF[1][1] = *(const bf16x8*)&sAc[aRd + 3072 + pc1];
        if (st) {
            GLDS16(bSt + 0 * 8 * KK + gk, sBn + (wave * 16 + 0) * 64);
            GLDS16(bSt + 1 * 8 * KK + gk, sBn + (wave * 16 + 8) * 64);
        }
        __builtin_amdgcn_s_barrier();
        asm volatile("s_waitcnt lgkmcnt(0)" ::: "memory");
        __builtin_amdgcn_s_setprio(1);
        acc[2][2] = MFMA16(aF[0][0], bF[1][0][0], acc[2][2], 0, 0, 0);
        acc[2][2] = MFMA16(aF[0][1], bF[1][0][1], acc[2][2], 0, 0, 0);
        acc[2][3] = MFMA16(aF[0][0], bF[1][1][0], acc[2][3], 0, 0, 0);
        acc[2][3] = MFMA16(aF[0][1], bF[1][1][1], acc[2][3], 0, 0, 0);
        acc[3][2] = MFMA16(aF[1][0], bF[1][0][0], acc[3][2], 0, 0, 0);
        acc[3][2] = MFMA16(aF[1][1], bF[1][0][1], acc[3][2], 0, 0, 0);
        acc[3][3] = MFMA16(aF[1][0], bF[1][1][0], acc[3][3], 0, 0, 0);
        acc[3][3] = MFMA16(aF[1][1], bF[1][1][1], acc[3][3], 0, 0, 0);
        __builtin_amdgcn_s_setprio(0);
        __builtin_amdgcn_s_barrier();

        // ---------- phase 3: m-frags 2,3 x n-frags 0,1 (regs only) ----------
        __builtin_amdgcn_s_setprio(1);
        acc[2][0] = MFMA16(aF[0][0], bF[0][0][0], acc[2][0], 0, 0, 0);
        acc[2][0] = MFMA16(aF[0][1], bF[0][0][1], acc[2][0], 0, 0, 0);
        acc[2][1] = MFMA16(aF[0][0], bF[0][1][0], acc[2][1], 0, 0, 0);
        acc[2][1] = MFMA16(aF[0][1], bF[0][1][1], acc[2][1], 0, 0, 0);
        acc[3][0] = MFMA16(aF[1][0], bF[0][0][0], acc[3][0], 0, 0, 0);
        acc[3][0] = MFMA16(aF[1][1], bF[0][0][1], acc[3][0], 0, 0, 0);
        acc[3][1] = MFMA16(aF[1][0], bF[0][1][0], acc[3][1], 0, 0, 0);
        acc[3][1] = MFMA16(aF[1][1], bF[0][1][1], acc[3][1], 0, 0, 0);
        __builtin_amdgcn_s_setprio(0);
        // counted wait: tile t+1 (oldest 6 of 12 outstanding) must land
        if (t < NT - 2) {
            asm volatile("s_waitcnt vmcnt(6)" ::: "memory");
        } else {
            asm volatile("s_waitcnt vmcnt(0)" ::: "memory");
        }
        __builtin_amdgcn_s_barrier();

        cur = (cur == 2) ? 0 : cur + 1;
    }

    // ---- epilogue: C/D layout col = lane&15, row = (lane>>4)*4 + reg ----
    float* Cp = C + (size_t)(bm + wm * 64) * NN + bn + wn * 64;
    const int cr = (lane >> 4) << 2;
    #pragma unroll
    for (int m = 0; m < 4; ++m) {
        #pragma unroll
        for (int j = 0; j < 4; ++j) {
            float* dst = Cp + (size_t)(m * 16 + cr + j) * NN + l15;
            #pragma unroll
            for (int n = 0; n < 4; ++n)
                dst[n * 16] = acc[m][n][j];
        }
    }
}

// ---------------- fallback: round-1 fused kernel ----------------
#define LDKF 72
__global__ __launch_bounds__(256) void wq4_gemm_fused(
    const float* __restrict__ A, const int* __restrict__ W,
    const float* __restrict__ SZ, float* __restrict__ C, int M)
{
    __shared__ short sA[128 * LDKF];
    __shared__ short sB[128 * LDKF];
    const int tid = threadIdx.x, lane = tid & 63, wave = tid >> 6;
    const int wr = (wave >> 1) << 6, wc = (wave & 1) << 6;
    const int bm = blockIdx.y * 128, bn = blockIdx.x * 128;
    const int ar = tid >> 2, ac = (tid & 3) << 4;
    const int br = tid >> 1, bh = (tid & 1) << 4;
    const float* Arow0 = A + (size_t)(bm + ar) * KK + ac;
    const float* Arow1 = A + (size_t)(bm + 64 + ar) * KK + ac;
    const int*   Wrow  = W + (size_t)(bn + br) * (KK / 2) + bh;
    const float* SZrow = SZ + (size_t)(bn + br) * 2;
    f32x4 acc[4][4] = {};
    for (int k0 = 0; k0 < KK; k0 += 64) {
        {
            const float4* s0 = (const float4*)(Arow0 + k0);
            const float4* s1 = (const float4*)(Arow1 + k0);
            float4 a0 = s0[0], a1 = s0[1], a2 = s0[2], a3 = s0[3];
            float4 b0 = s1[0], b1 = s1[1], b2 = s1[2], b3 = s1[3];
            auto cvt8 = [](float4 u, float4 v) -> bf16x8 {
                bf16x8 r;
                r[0] = f2bf(u.x); r[1] = f2bf(u.y); r[2] = f2bf(u.z); r[3] = f2bf(u.w);
                r[4] = f2bf(v.x); r[5] = f2bf(v.y); r[6] = f2bf(v.z); r[7] = f2bf(v.w);
                return r;
            };
            *(bf16x8*)&sA[ar * LDKF + ac]            = cvt8(a0, a1);
            *(bf16x8*)&sA[ar * LDKF + ac + 8]        = cvt8(a2, a3);
            *(bf16x8*)&sA[(64 + ar) * LDKF + ac]     = cvt8(b0, b1);
            *(bf16x8*)&sA[(64 + ar) * LDKF + ac + 8] = cvt8(b2, b3);
        }
        {
            const int g = k0 >> 7;
            const float2 sz = *(const float2*)(SZrow + (size_t)g * NN * 2);
            const float scale = sz.x, zs = sz.y - 8.0f * sz.x;
            const int4* src = (const int4*)(Wrow + (k0 >> 1));
            #pragma unroll
            for (int i = 0; i < 4; ++i) {
                int4 p = src[i];
                int vals[4] = {p.x, p.y, p.z, p.w};
                bf16x8 r;
                #pragma unroll
                for (int j = 0; j < 4; ++j) {
                    int v = vals[j];
                    r[2 * j]     = f2bf((float)((v >> 4) & 0xF) * scale + zs);
                    r[2 * j + 1] = f2bf((float)(v & 0xF) * scale + zs);
                }
                *(bf16x8*)&sB[br * LDKF + (bh << 1) + (i << 3)] = r;
            }
        }
        __syncthreads();
        #pragma unroll
        for (int ks = 0; ks < 2; ++ks) {
            const int col = (ks << 5) + ((lane >> 4) << 3);
            bf16x8 af[4], bfr[4];
            #pragma unroll
            for (int m = 0; m < 4; ++m)
                af[m] = *(const bf16x8*)&sA[(wr + m * 16 + (lane & 15)) * LDKF + col];
            #pragma unroll
            for (int n = 0; n < 4; ++n)
                bfr[n] = *(const bf16x8*)&sB[(wc + n * 16 + (lane & 15)) * LDKF + col];
            #pragma unroll
            for (int m = 0; m < 4; ++m)
                #pragma unroll
                for (int n = 0; n < 4; ++n)
                    acc[m][n] = __builtin_amdgcn_mfma_f32_16x16x32_bf16(
                        af[m], bfr[n], acc[m][n], 0, 0, 0);
        }
        __syncthreads();
    }
    float* Cp = C + (size_t)(bm + wr) * NN + bn + wc;
    const int cr = (lane >> 4) << 2, cc = lane & 15;
    #pragma unroll
    for (int m = 0; m < 4; ++m)
        #pragma unroll
        for (int j = 0; j < 4; ++j) {
            float* dst = Cp + (size_t)(m * 16 + cr + j) * NN + cc;
            #pragma unroll
            for (int n = 0; n < 4; ++n) dst[n * 16] = acc[m][n][j];
        }
}

extern "C" void kernel_launch(void* const* d_in, const int* in_sizes, int n_in,
                              void* d_out, int out_size, void* d_ws, size_t ws_size,
                              hipStream_t stream) {
    const float* A  = (const float*)d_in[0];
    const int*   W  = (const int*)d_in[1];
    const float* SZ = (const float*)d_in[2];
    float* C = (float*)d_out;

    const int M = in_sizes[0] / KK;   // 2048

    const size_t wd_elems = (size_t)NN * KK;
    const size_t ab_elems = (size_t)M * KK;
    const size_t need = (wd_elems + ab_elems) * sizeof(short);

    if (ws_size >= need && (M % 256) == 0) {
        short* Wd = (short*)d_ws;
        short* Ab = Wd + wd_elems;
        dequant_w<<<NN * (KK / 8) / 256, 256, 0, stream>>>(W, SZ, Wd);
        cvt_a<<<(int)(ab_elems / 8 / 256), 256, 0, stream>>>(A, Ab);
        dim3 grid(NN / 128, M / 256);
        gemm_8ph<<<grid, dim3(512), 0, stream>>>(Ab, Wd, C);
    } else {
        dim3 grid(NN / 128, M / 128);
        wq4_gemm_fused<<<grid, dim3(256), 0, stream>>>(A, W, SZ, C, M);
    }
}